// Round 3
// baseline (5466.825 us; speedup 1.0000x reference)
//
#include <hip/hip_runtime.h>
#include <hip/hip_bf16.h>

// RNN: outs[t] = h_t = tanh(x[t]@Wx + b + h_{t-1}@Wh), T=512,B=64,IN=512,H=1024
// Strategy:
//  - split-bf16 (hi+lo) MFMA everywhere (no fp32 MFMA on CDNA4); 3-term product
//  - phase A: xw = x@Wx+b written directly into d_out (overwritten by h_t in place)
//  - scan: 128 persistent wgs = 4 batch-groups(16 rows) x 32 col-groups(32 cols),
//    Wh fragments REGISTER-resident across all 512 steps (K split over 4 waves),
//    h ping-pong as bf16 hi/lo in ws, agent-scope (coherent) h traffic only.
//  - R1: no fences in loop; only h traffic device-coherent; was 15.5 -> 9.5 us/step.
//  - R2: barrier rebuilt lock-free: flag-per-producer (32 words = 1 line per (g,t),
//    release store) + per-wave parallel poll (lanes 0..31 load all 32 flags in one
//    transaction, __all exit). Removes 32-deep atomic-RMW serialization.
//    xw[t+1] prefetched before the store-drain barrier; acc chains split by parity.

#define T_ 512
#define B_ 64
#define IN_ 512
#define H_ 1024
constexpr int TBH = T_ * B_ * H_;   // 33,554,432
constexpr int HB  = B_ * H_;        // 65,536

typedef unsigned short u16;
typedef unsigned long long u64;
typedef __attribute__((ext_vector_type(8))) short short8;   // 8 x bf16 (4 VGPRs)
typedef __attribute__((ext_vector_type(4))) float f32x4;

__device__ __forceinline__ void splitbf(float x, u16& hi, u16& lo) {
    unsigned u = __float_as_uint(x);
    hi = (u16)(u >> 16);                       // truncated bf16 hi
    float r = x - __uint_as_float(u & 0xffff0000u);
    lo = (u16)(__float_as_uint(r) >> 16);      // bf16 of residual; total rel err ~2^-16
}

// device-coherent load of 8 bf16 (two 8B agent-scope loads; bypass stale caches)
__device__ __forceinline__ short8 load8_coh(const u16* p) {
    u64 a = __hip_atomic_load((const u64*)p,     __ATOMIC_RELAXED, __HIP_MEMORY_SCOPE_AGENT);
    u64 b = __hip_atomic_load((const u64*)p + 1, __ATOMIC_RELAXED, __HIP_MEMORY_SCOPE_AGENT);
    union { u64 q[2]; short8 v; } u;
    u.q[0] = a; u.q[1] = b;
    return u.v;
}

__device__ __forceinline__ void store4_coh(u16* p, unsigned v) {
    __hip_atomic_store((unsigned*)p, v, __ATOMIC_RELAXED, __HIP_MEMORY_SCOPE_AGENT);
}

// ---- prep kernels ------------------------------------------------------------
__global__ void k_split4(const float4* __restrict__ in, u16* __restrict__ hi,
                         u16* __restrict__ lo, int n4) {
    int i = blockIdx.x * blockDim.x + threadIdx.x;
    int stride = gridDim.x * blockDim.x;
    for (; i < n4; i += stride) {
        float4 v = in[i];
        u16 h0,h1,h2,h3,l0,l1,l2,l3;
        splitbf(v.x,h0,l0); splitbf(v.y,h1,l1); splitbf(v.z,h2,l2); splitbf(v.w,h3,l3);
        uint2 hv, lv;
        hv.x = (unsigned)h0 | ((unsigned)h1 << 16);
        hv.y = (unsigned)h2 | ((unsigned)h3 << 16);
        lv.x = (unsigned)l0 | ((unsigned)l1 << 16);
        lv.y = (unsigned)l2 | ((unsigned)l3 << 16);
        *(uint2*)&hi[4*i] = hv;
        *(uint2*)&lo[4*i] = lv;
    }
}

// src [K][N] fp32 -> dst [N][K] bf16 hi/lo (transposed for B-fragment reads)
__global__ void k_tsplit(const float* __restrict__ src, u16* __restrict__ hi,
                         u16* __restrict__ lo, int K, int N) {
    int id = blockIdx.x * 256 + threadIdx.x;
    if (id >= K * N) return;
    int k = id / N, n = id % N;
    u16 h, l; splitbf(src[id], h, l);
    hi[n*K + k] = h; lo[n*K + k] = l;
}

// h0 fp32 -> hbuf buffer 1 (read at t=0)
__global__ void k_h0(const float* __restrict__ h0, u16* __restrict__ hbuf) {
    int id = blockIdx.x * 256 + threadIdx.x;
    if (id >= HB) return;
    u16 h, l; splitbf(h0[id], h, l);
    hbuf[2*HB + id] = h;   // [buf=1][hi]
    hbuf[3*HB + id] = l;   // [buf=1][lo]
}

// ---- phase A: xw = x@Wx + b, split-bf16 MFMA, 128x128 tile, frags from global -
__launch_bounds__(256, 2)
__global__ void k_gemm_xw(const u16* __restrict__ xhi, const u16* __restrict__ xlo,
                          const u16* __restrict__ wthi, const u16* __restrict__ wtlo,
                          const float* __restrict__ bias, float* __restrict__ out) {
    int bid = blockIdx.x;
    int mi = bid >> 3, ni = bid & 7;
    int m0 = mi * 128, n0 = ni * 128;
    int wave = threadIdx.x >> 6, lane = threadIdx.x & 63;
    int wr = wave >> 1, wc = wave & 1;
    int lrow = lane & 15, lk8 = (lane >> 4) * 8;
    const int rowb = m0 + wr*64 + lrow;   // A row for this lane
    const int colb = n0 + wc*64 + lrow;   // B col for this lane
    f32x4 acc[4][4] = {};
    for (int kt = 0; kt < 16; ++kt) {
        int kb = kt*32 + lk8;
        short8 ah[4], al[4], bh[4], bl[4];
#pragma unroll
        for (int mt = 0; mt < 4; ++mt) {
            ah[mt] = *(const short8*)&xhi[(size_t)(rowb + mt*16)*IN_ + kb];
            al[mt] = *(const short8*)&xlo[(size_t)(rowb + mt*16)*IN_ + kb];
        }
#pragma unroll
        for (int nt = 0; nt < 4; ++nt) {
            bh[nt] = *(const short8*)&wthi[(size_t)(colb + nt*16)*IN_ + kb];
            bl[nt] = *(const short8*)&wtlo[(size_t)(colb + nt*16)*IN_ + kb];
        }
#pragma unroll
        for (int mt = 0; mt < 4; ++mt)
#pragma unroll
            for (int nt = 0; nt < 4; ++nt) {
                acc[mt][nt] = __builtin_amdgcn_mfma_f32_16x16x32_bf16(ah[mt], bh[nt], acc[mt][nt], 0,0,0);
                acc[mt][nt] = __builtin_amdgcn_mfma_f32_16x16x32_bf16(ah[mt], bl[nt], acc[mt][nt], 0,0,0);
                acc[mt][nt] = __builtin_amdgcn_mfma_f32_16x16x32_bf16(al[mt], bh[nt], acc[mt][nt], 0,0,0);
            }
    }
    // epilogue: D layout col=lane&15, row=4*(lane>>4)+reg
    int orow0 = m0 + wr*64 + 4*(lane >> 4);
#pragma unroll
    for (int nt = 0; nt < 4; ++nt) {
        int col = n0 + wc*64 + nt*16 + (lane & 15);
        float bv = bias[col];
#pragma unroll
        for (int mt = 0; mt < 4; ++mt)
#pragma unroll
            for (int r = 0; r < 4; ++r)
                out[(size_t)(orow0 + mt*16 + r)*H_ + col] = acc[mt][nt][r] + bv;
    }
}

// ---- phase A fallback (fp32 vector) if ws too small for split buffers --------
__global__ void k_gemm_f32(const float* __restrict__ A, const float* __restrict__ Bw,
                           const float* __restrict__ bias, float* __restrict__ out) {
    __shared__ float As[32][65];  // [k][m]
    __shared__ float Bs[32][65];  // [k][n]
    int n0 = blockIdx.x * 64, m0 = blockIdx.y * 64;
    int tid = threadIdx.x;
    int tr = tid >> 4, tc = tid & 15;
    float acc[4][4] = {};
    for (int kc = 0; kc < IN_; kc += 32) {
#pragma unroll
        for (int it = 0; it < 8; ++it) {
            int id = tid + 256*it;
            int k = id & 31, m = id >> 5;
            As[k][m] = A[(size_t)(m0 + m)*IN_ + kc + k];
        }
#pragma unroll
        for (int it = 0; it < 8; ++it) {
            int id = tid + 256*it;
            int n = id & 63, kk = id >> 6;
            Bs[kk][n] = Bw[(size_t)(kc + kk)*H_ + n0 + n];
        }
        __syncthreads();
#pragma unroll
        for (int kk = 0; kk < 32; ++kk) {
            float a[4], b[4];
#pragma unroll
            for (int i = 0; i < 4; ++i) a[i] = As[kk][tr*4+i];
#pragma unroll
            for (int j = 0; j < 4; ++j) b[j] = Bs[kk][tc*4+j];
#pragma unroll
            for (int i = 0; i < 4; ++i)
#pragma unroll
                for (int j = 0; j < 4; ++j) acc[i][j] += a[i]*b[j];
        }
        __syncthreads();
    }
#pragma unroll
    for (int i = 0; i < 4; ++i)
#pragma unroll
        for (int j = 0; j < 4; ++j)
            out[(size_t)(m0 + tr*4 + i)*H_ + n0 + tc*4 + j] = acc[i][j] + bias[n0 + tc*4 + j];
}

// ---- scan: persistent, Wh register-resident, lock-free flag barrier ----------
__launch_bounds__(256, 1)
__global__ void k_scan(const float* __restrict__ wh,   // [H][H] fp32 (k-major)
                       float* __restrict__ out,        // [T][B][H] xw in / h out, + tail h_last
                       u16* __restrict__ hbuf,         // [2 buf][2 hl][B][H] bf16
                       int* __restrict__ flags) {      // [4 groups][T][32 producers]
    int bid = blockIdx.x;
    int g = bid >> 5, cg = bid & 31;
    int n0 = cg * 32;
    int row_g = g * 16;
    int wave = threadIdx.x >> 6, lane = threadIdx.x & 63;
    int lrow = lane & 15, lk8 = (lane >> 4) * 8;
    __shared__ float partial[4 * 16 * 33];   // [wave][row][col(+pad)]

    // Load Wh fragments ONCE: this wave covers k in [wave*256, wave*256+256)
    short8 bh[2][8], bl[2][8];
#pragma unroll
    for (int nt = 0; nt < 2; ++nt) {
        int col = n0 + nt*16 + lrow;
#pragma unroll
        for (int kt = 0; kt < 8; ++kt) {
            int kbase = wave*256 + kt*32 + lk8;
            short8 h8, l8;
#pragma unroll
            for (int j = 0; j < 8; ++j) {
                u16 hh, ll; splitbf(wh[(size_t)(kbase + j)*H_ + col], hh, ll);
                h8[j] = (short)hh; l8[j] = (short)ll;
            }
            bh[nt][kt] = h8; bl[nt][kt] = l8;
        }
    }

    // epilogue indexing: row er, col-pair ec0
    const int er = threadIdx.x >> 4;         // 0..15
    const int ec0 = (threadIdx.x & 15) * 2;  // 0,2,..,30

    // prefetch xw for t=0
    float2 xwv = *(const float2*)&out[(size_t)(0*B_ + row_g + er)*H_ + n0 + ec0];

    for (int t = 0; t < T_; ++t) {
        const u16* hHi = hbuf + (size_t)(((t+1)&1)*2 + 0)*HB;   // h_{t-1}
        const u16* hLo = hbuf + (size_t)(((t+1)&1)*2 + 1)*HB;
        u16* nHi = hbuf + (size_t)((t&1)*2 + 0)*HB;             // h_t
        u16* nLo = hbuf + (size_t)((t&1)*2 + 1)*HB;

        // issue ALL coherent h loads first (overlap latency)
        short8 ah[8], al[8];
#pragma unroll
        for (int kt = 0; kt < 8; ++kt) {
            int kbase = wave*256 + kt*32 + lk8;
            const size_t off = (size_t)(row_g + lrow)*H_ + kbase;
            ah[kt] = load8_coh(&hHi[off]);
            al[kt] = load8_coh(&hLo[off]);
        }

        // parity-split accumulator chains (12-deep instead of 24-deep)
        f32x4 acc[2][2] = {};
#pragma unroll
        for (int kt = 0; kt < 8; ++kt) {
            int p = kt & 1;
#pragma unroll
            for (int nt = 0; nt < 2; ++nt) {
                acc[nt][p] = __builtin_amdgcn_mfma_f32_16x16x32_bf16(ah[kt], bh[nt][kt], acc[nt][p], 0,0,0);
                acc[nt][p] = __builtin_amdgcn_mfma_f32_16x16x32_bf16(ah[kt], bl[nt][kt], acc[nt][p], 0,0,0);
                acc[nt][p] = __builtin_amdgcn_mfma_f32_16x16x32_bf16(al[kt], bh[nt][kt], acc[nt][p], 0,0,0);
            }
        }
        // K-partials to LDS: [wave][row][col], row=4*(lane>>4)+r, col=nt*16+lrow
        {
            int r0 = 4 * (lane >> 4);
#pragma unroll
            for (int nt = 0; nt < 2; ++nt) {
                int c = nt*16 + lrow;
#pragma unroll
                for (int r = 0; r < 4; ++r)
                    partial[(wave*16 + r0 + r)*33 + c] = acc[nt][0][r] + acc[nt][1][r];
            }
        }
        __syncthreads();
        // reduce 4 K-partials + xw, tanh, write h (coherent) + out (plain)
        {
            float s0 = xwv.x, s1 = xwv.y;
#pragma unroll
            for (int w = 0; w < 4; ++w) {
                s0 += partial[(w*16 + er)*33 + ec0];
                s1 += partial[(w*16 + er)*33 + ec0 + 1];
            }
            float y0 = tanhf(s0), y1 = tanhf(s1);
            int gb = row_g + er;
            *(float2*)&out[(size_t)(t*B_ + gb)*H_ + n0 + ec0] = make_float2(y0, y1);
            u16 h0,l0,h1,l1;
            splitbf(y0,h0,l0); splitbf(y1,h1,l1);
            store4_coh(&nHi[(size_t)gb*H_ + n0 + ec0], (unsigned)h0 | ((unsigned)h1 << 16));
            store4_coh(&nLo[(size_t)gb*H_ + n0 + ec0], (unsigned)l0 | ((unsigned)l1 << 16));
            if (t == T_-1)
                *(float2*)&out[(size_t)TBH + (size_t)gb*H_ + n0 + ec0] = make_float2(y0, y1);
        }
        // prefetch next xw NOW; its latency hides under the barrier's vmcnt drain
        if (t + 1 < T_)
            xwv = *(const float2*)&out[(size_t)((t+1)*B_ + row_g + er)*H_ + n0 + ec0];

        __syncthreads();   // every thread's h stores drained (vmcnt(0) per wave)

        // producer flag: one release store into our own slot (no RMW)
        if (threadIdx.x == 0)
            __hip_atomic_store(&flags[((size_t)g*T_ + t)*32 + cg], 1,
                               __ATOMIC_RELEASE, __HIP_MEMORY_SCOPE_AGENT);

        // per-wave parallel poll: lanes 0..31 read all 32 flags in one transaction
        {
            const int* fptr = &flags[((size_t)g*T_ + t)*32];
            int done;
            do {
                int v = 1;
                if (lane < 32)
                    v = __hip_atomic_load(&fptr[lane], __ATOMIC_RELAXED,
                                          __HIP_MEMORY_SCOPE_AGENT);
                done = __all(v != 0);
                if (!done) __builtin_amdgcn_s_sleep(2);
            } while (!done);
        }
        asm volatile("" ::: "memory");   // keep next h loads below the poll
    }
}

// ---- host --------------------------------------------------------------------
extern "C" void kernel_launch(void* const* d_in, const int* in_sizes, int n_in,
                              void* d_out, int out_size, void* d_ws, size_t ws_size,
                              hipStream_t stream) {
    const float* x    = (const float*)d_in[0];
    const float* h0   = (const float*)d_in[1];
    const float* Wx   = (const float*)d_in[2];
    const float* Wh   = (const float*)d_in[3];
    const float* bias = (const float*)d_in[4];
    float* out = (float*)d_out;

    const size_t nX = (size_t)T_ * B_ * IN_;            // 16,777,216
    const size_t nWx = (size_t)IN_ * H_;                // 524,288
    const size_t hbufB = (size_t)4 * HB * sizeof(u16);  // 512 KB
    const size_t flagB = (size_t)4 * T_ * 32 * sizeof(int);  // 256 KB
    const size_t FULL_NEED = 2*nX*2 + 2*nWx*2 + hbufB + flagB;   // ~66.8 MiB
    const size_t SAFE_NEED = hbufB + flagB;
    if (ws_size < SAFE_NEED) return;   // cannot run; fail loudly

    bool full = ws_size >= FULL_NEED;
    u16 *xhi, *xlo, *wthi, *wtlo, *hbuf;
    if (full) {
        xhi  = (u16*)d_ws;
        xlo  = xhi + nX;
        wthi = xlo + nX;
        wtlo = wthi + nWx;
        hbuf = wtlo + nWx;
    } else {
        hbuf = (u16*)d_ws;
    }
    int* flags = (int*)(hbuf + 4*HB);

    hipMemsetAsync(flags, 0, flagB, stream);
    k_h0<<<HB/256, 256, 0, stream>>>(h0, hbuf);
    if (full) {
        k_split4<<<2048, 256, 0, stream>>>((const float4*)x, xhi, xlo, (int)(nX/4));
        k_tsplit<<<(int)(nWx/256), 256, 0, stream>>>(Wx, wthi, wtlo, IN_, H_);
        k_gemm_xw<<<2048, 256, 0, stream>>>(xhi, xlo, wthi, wtlo, bias, out);
    } else {
        k_gemm_f32<<<dim3(16, 512), 256, 0, stream>>>(x, Wx, bias, out);
    }
    k_scan<<<128, 256, 0, stream>>>(Wh, out, hbuf, flags);
}

// Round 4
// 3564.388 us; speedup vs baseline: 1.5337x; 1.5337x over previous
//
#include <hip/hip_runtime.h>
#include <hip/hip_bf16.h>

// RNN: outs[t] = h_t = tanh(x[t]@Wx + b + h_{t-1}@Wh), T=512,B=64,IN=512,H=1024
// Strategy:
//  - split-bf16 (hi+lo) MFMA everywhere (no fp32 MFMA on CDNA4); 3-term product
//  - phase A: xw = x@Wx+b written directly into d_out (overwritten by h_t in place)
//  - scan: 128 persistent wgs = 4 batch-groups(16 rows) x 32 col-groups(32 cols),
//    Wh fragments REGISTER-resident across all 512 steps (K split over 4 waves).
//  - R1: coherent-h-only (no fences): 15.5 -> 9.5 us/step.
//  - R2: lock-free flag barrier: REGRESSED (10.2) -> barrier cost is serialized
//    IC round-trip LEGS (drain, flag, observe, load), not fan-in.
//  - R3: SELF-VALIDATING h: store h as f32 with low 7 mantissa bits = epoch tag
//    (64|(t&63)). No flags, no drains, no barriers. Consumer's poll IS the data
//    load: retry agent-loads of its slice until every word's tag matches; data
//    is then already in registers. 4 IC legs -> ~1.5. Tag range [64,127] can
//    never match memset-0 (tag 0) or 0xAA poison (tag 42); aliasing needs
//    128-step skew, impossible (group members lockstep +-1 step).

#define T_ 512
#define B_ 64
#define IN_ 512
#define H_ 1024
constexpr int TBH = T_ * B_ * H_;   // 33,554,432
constexpr int HB  = B_ * H_;        // 65,536

typedef unsigned short u16;
typedef unsigned int u32;
typedef unsigned long long u64;
typedef __attribute__((ext_vector_type(8))) short short8;   // 8 x bf16 (4 VGPRs)
typedef __attribute__((ext_vector_type(4))) float f32x4;

__device__ __forceinline__ void splitbf(float x, u16& hi, u16& lo) {
    unsigned u = __float_as_uint(x);
    hi = (u16)(u >> 16);                       // truncated bf16 hi
    float r = x - __uint_as_float(u & 0xffff0000u);
    lo = (u16)(__float_as_uint(r) >> 16);      // bf16 of residual; total rel err ~2^-16
}

// ---- prep kernels ------------------------------------------------------------
__global__ void k_split4(const float4* __restrict__ in, u16* __restrict__ hi,
                         u16* __restrict__ lo, int n4) {
    int i = blockIdx.x * blockDim.x + threadIdx.x;
    int stride = gridDim.x * blockDim.x;
    for (; i < n4; i += stride) {
        float4 v = in[i];
        u16 h0,h1,h2,h3,l0,l1,l2,l3;
        splitbf(v.x,h0,l0); splitbf(v.y,h1,l1); splitbf(v.z,h2,l2); splitbf(v.w,h3,l3);
        uint2 hv, lv;
        hv.x = (unsigned)h0 | ((unsigned)h1 << 16);
        hv.y = (unsigned)h2 | ((unsigned)h3 << 16);
        lv.x = (unsigned)l0 | ((unsigned)l1 << 16);
        lv.y = (unsigned)l2 | ((unsigned)l3 << 16);
        *(uint2*)&hi[4*i] = hv;
        *(uint2*)&lo[4*i] = lv;
    }
}

// src [K][N] fp32 -> dst [N][K] bf16 hi/lo (transposed for B-fragment reads)
__global__ void k_tsplit(const float* __restrict__ src, u16* __restrict__ hi,
                         u16* __restrict__ lo, int K, int N) {
    int id = blockIdx.x * 256 + threadIdx.x;
    if (id >= K * N) return;
    int k = id / N, n = id % N;
    u16 h, l; splitbf(src[id], h, l);
    hi[n*K + k] = h; lo[n*K + k] = l;
}

// h0 fp32 -> tagged-f32 into hbuf parity-1 (read at t=0, expects tag 127)
__global__ void k_h0(const float* __restrict__ h0, u32* __restrict__ hbuf) {
    int id = blockIdx.x * 256 + threadIdx.x;
    if (id >= HB) return;
    u32 u = __float_as_uint(h0[id]);
    hbuf[HB + id] = (u & 0xFFFFFF80u) | 127u;   // tag(s=-1) = 64|63 = 127
}

// ---- phase A: xw = x@Wx + b, split-bf16 MFMA, 128x128 tile, frags from global -
__launch_bounds__(256, 2)
__global__ void k_gemm_xw(const u16* __restrict__ xhi, const u16* __restrict__ xlo,
                          const u16* __restrict__ wthi, const u16* __restrict__ wtlo,
                          const float* __restrict__ bias, float* __restrict__ out) {
    int bid = blockIdx.x;
    int mi = bid >> 3, ni = bid & 7;
    int m0 = mi * 128, n0 = ni * 128;
    int wave = threadIdx.x >> 6, lane = threadIdx.x & 63;
    int wr = wave >> 1, wc = wave & 1;
    int lrow = lane & 15, lk8 = (lane >> 4) * 8;
    const int rowb = m0 + wr*64 + lrow;   // A row for this lane
    const int colb = n0 + wc*64 + lrow;   // B col for this lane
    f32x4 acc[4][4] = {};
    for (int kt = 0; kt < 16; ++kt) {
        int kb = kt*32 + lk8;
        short8 ah[4], al[4], bh[4], bl[4];
#pragma unroll
        for (int mt = 0; mt < 4; ++mt) {
            ah[mt] = *(const short8*)&xhi[(size_t)(rowb + mt*16)*IN_ + kb];
            al[mt] = *(const short8*)&xlo[(size_t)(rowb + mt*16)*IN_ + kb];
        }
#pragma unroll
        for (int nt = 0; nt < 4; ++nt) {
            bh[nt] = *(const short8*)&wthi[(size_t)(colb + nt*16)*IN_ + kb];
            bl[nt] = *(const short8*)&wtlo[(size_t)(colb + nt*16)*IN_ + kb];
        }
#pragma unroll
        for (int mt = 0; mt < 4; ++mt)
#pragma unroll
            for (int nt = 0; nt < 4; ++nt) {
                acc[mt][nt] = __builtin_amdgcn_mfma_f32_16x16x32_bf16(ah[mt], bh[nt], acc[mt][nt], 0,0,0);
                acc[mt][nt] = __builtin_amdgcn_mfma_f32_16x16x32_bf16(ah[mt], bl[nt], acc[mt][nt], 0,0,0);
                acc[mt][nt] = __builtin_amdgcn_mfma_f32_16x16x32_bf16(al[mt], bh[nt], acc[mt][nt], 0,0,0);
            }
    }
    // epilogue: D layout col=lane&15, row=4*(lane>>4)+reg
    int orow0 = m0 + wr*64 + 4*(lane >> 4);
#pragma unroll
    for (int nt = 0; nt < 4; ++nt) {
        int col = n0 + wc*64 + nt*16 + (lane & 15);
        float bv = bias[col];
#pragma unroll
        for (int mt = 0; mt < 4; ++mt)
#pragma unroll
            for (int r = 0; r < 4; ++r)
                out[(size_t)(orow0 + mt*16 + r)*H_ + col] = acc[mt][nt][r] + bv;
    }
}

// ---- phase A fallback (fp32 vector) if ws too small for split buffers --------
__global__ void k_gemm_f32(const float* __restrict__ A, const float* __restrict__ Bw,
                           const float* __restrict__ bias, float* __restrict__ out) {
    __shared__ float As[32][65];  // [k][m]
    __shared__ float Bs[32][65];  // [k][n]
    int n0 = blockIdx.x * 64, m0 = blockIdx.y * 64;
    int tid = threadIdx.x;
    int tr = tid >> 4, tc = tid & 15;
    float acc[4][4] = {};
    for (int kc = 0; kc < IN_; kc += 32) {
#pragma unroll
        for (int it = 0; it < 8; ++it) {
            int id = tid + 256*it;
            int k = id & 31, m = id >> 5;
            As[k][m] = A[(size_t)(m0 + m)*IN_ + kc + k];
        }
#pragma unroll
        for (int it = 0; it < 8; ++it) {
            int id = tid + 256*it;
            int n = id & 63, kk = id >> 6;
            Bs[kk][n] = Bw[(size_t)(kc + kk)*H_ + n0 + n];
        }
        __syncthreads();
#pragma unroll
        for (int kk = 0; kk < 32; ++kk) {
            float a[4], b[4];
#pragma unroll
            for (int i = 0; i < 4; ++i) a[i] = As[kk][tr*4+i];
#pragma unroll
            for (int j = 0; j < 4; ++j) b[j] = Bs[kk][tc*4+j];
#pragma unroll
            for (int i = 0; i < 4; ++i)
#pragma unroll
                for (int j = 0; j < 4; ++j) acc[i][j] += a[i]*b[j];
        }
        __syncthreads();
    }
#pragma unroll
    for (int i = 0; i < 4; ++i)
#pragma unroll
        for (int j = 0; j < 4; ++j)
            out[(size_t)(m0 + tr*4 + i)*H_ + n0 + tc*4 + j] = acc[i][j] + bias[n0 + tc*4 + j];
}

// ---- scan: persistent, Wh register-resident, self-validating h exchange ------
__launch_bounds__(256, 1)
__global__ void k_scan(const float* __restrict__ wh,   // [H][H] fp32 (k-major)
                       float* __restrict__ out,        // [T][B][H] xw in / h out, + tail h_last
                       u32* __restrict__ hbuf) {       // [2 parity][B][H] tagged f32
    int bid = blockIdx.x;
    int g = bid >> 5, cg = bid & 31;
    int n0 = cg * 32;
    int row_g = g * 16;
    int wave = threadIdx.x >> 6, lane = threadIdx.x & 63;
    int lrow = lane & 15, lk8 = (lane >> 4) * 8;
    __shared__ float partial[2 * 4 * 16 * 33];   // [parity][wave][row][col(+pad)]

    // Load Wh fragments ONCE: this wave covers k in [wave*256, wave*256+256)
    short8 bh[2][8], bl[2][8];
#pragma unroll
    for (int nt = 0; nt < 2; ++nt) {
        int col = n0 + nt*16 + lrow;
#pragma unroll
        for (int kt = 0; kt < 8; ++kt) {
            int kbase = wave*256 + kt*32 + lk8;
            short8 h8, l8;
#pragma unroll
            for (int j = 0; j < 8; ++j) {
                u16 hh, ll; splitbf(wh[(size_t)(kbase + j)*H_ + col], hh, ll);
                h8[j] = (short)hh; l8[j] = (short)ll;
            }
            bh[nt][kt] = h8; bl[nt][kt] = l8;
        }
    }

    // epilogue indexing: row er, col-pair ec0
    const int er = threadIdx.x >> 4;         // 0..15
    const int ec0 = (threadIdx.x & 15) * 2;  // 0,2,..,30

    // prefetch xw for t=0
    float2 xwv = *(const float2*)&out[(size_t)(0*B_ + row_g + er)*H_ + n0 + ec0];

    for (int t = 0; t < T_; ++t) {
        const u32* hprev = hbuf + (size_t)((t+1)&1)*HB;   // h_{t-1} tagged
        u32* hnew = hbuf + (size_t)(t&1)*HB;              // h_t tagged
        const unsigned want = 64u | (unsigned)((t - 1) & 63);   // tag of h_{t-1}
        const int par = t & 1;

        // ---- self-validating retry-load of this wave's h slice ----
        u64 raw[32];
        const u64* base = (const u64*)&hprev[(size_t)(row_g + lrow)*H_ + wave*256 + lk8];
        for (;;) {
#pragma unroll
            for (int kt = 0; kt < 8; ++kt) {
                const u64* p = base + kt * 16;   // +32 f32 per kt = 16 u64
                raw[kt*4+0] = __hip_atomic_load(p+0, __ATOMIC_RELAXED, __HIP_MEMORY_SCOPE_AGENT);
                raw[kt*4+1] = __hip_atomic_load(p+1, __ATOMIC_RELAXED, __HIP_MEMORY_SCOPE_AGENT);
                raw[kt*4+2] = __hip_atomic_load(p+2, __ATOMIC_RELAXED, __HIP_MEMORY_SCOPE_AGENT);
                raw[kt*4+3] = __hip_atomic_load(p+3, __ATOMIC_RELAXED, __HIP_MEMORY_SCOPE_AGENT);
            }
            unsigned bad = 0;
#pragma unroll
            for (int i = 0; i < 32; ++i) {
                bad |= ((unsigned)raw[i] ^ want) & 127u;
                bad |= ((unsigned)(raw[i] >> 32) ^ want) & 127u;
            }
            if (__all(bad == 0)) break;
            __builtin_amdgcn_s_sleep(1);
        }

        // ---- convert tagged f32 -> bf16 hi/lo fragments ----
        short8 ah[8], al[8];
#pragma unroll
        for (int kt = 0; kt < 8; ++kt) {
#pragma unroll
            for (int j = 0; j < 8; ++j) {
                u32 bits = (j & 1) ? (u32)(raw[kt*4 + (j>>1)] >> 32)
                                   : (u32)(raw[kt*4 + (j>>1)]);
                ah[kt][j] = (short)(bits >> 16);
                float r = __uint_as_float(bits & 0xFFFFFF80u)
                        - __uint_as_float(bits & 0xFFFF0000u);
                al[kt][j] = (short)(__float_as_uint(r) >> 16);
            }
        }

        // ---- MFMA (parity-split chains) ----
        f32x4 acc[2][2] = {};
#pragma unroll
        for (int kt = 0; kt < 8; ++kt) {
            int p = kt & 1;
#pragma unroll
            for (int nt = 0; nt < 2; ++nt) {
                acc[nt][p] = __builtin_amdgcn_mfma_f32_16x16x32_bf16(ah[kt], bh[nt][kt], acc[nt][p], 0,0,0);
                acc[nt][p] = __builtin_amdgcn_mfma_f32_16x16x32_bf16(ah[kt], bl[nt][kt], acc[nt][p], 0,0,0);
                acc[nt][p] = __builtin_amdgcn_mfma_f32_16x16x32_bf16(al[kt], bh[nt][kt], acc[nt][p], 0,0,0);
            }
        }
        // K-partials to LDS (parity double-buffer): row=4*(lane>>4)+r, col=nt*16+lrow
        {
            int r0 = 4 * (lane >> 4);
#pragma unroll
            for (int nt = 0; nt < 2; ++nt) {
                int c = nt*16 + lrow;
#pragma unroll
                for (int r = 0; r < 4; ++r)
                    partial[((par*4 + wave)*16 + r0 + r)*33 + c] = acc[nt][0][r] + acc[nt][1][r];
            }
        }
        __syncthreads();
        // ---- reduce + tanh + stores ----
        {
            float s0 = xwv.x, s1 = xwv.y;
#pragma unroll
            for (int w = 0; w < 4; ++w) {
                s0 += partial[((par*4 + w)*16 + er)*33 + ec0];
                s1 += partial[((par*4 + w)*16 + er)*33 + ec0 + 1];
            }
            float y0 = tanhf(s0), y1 = tanhf(s1);
            int gb = row_g + er;
            *(float2*)&out[(size_t)(t*B_ + gb)*H_ + n0 + ec0] = make_float2(y0, y1);
            const unsigned tagt = 64u | (unsigned)(t & 63);
            u32 b0 = (__float_as_uint(y0) & 0xFFFFFF80u) | tagt;
            u32 b1 = (__float_as_uint(y1) & 0xFFFFFF80u) | tagt;
            __hip_atomic_store((u64*)&hnew[(size_t)gb*H_ + n0 + ec0],
                               ((u64)b1 << 32) | (u64)b0,
                               __ATOMIC_RELAXED, __HIP_MEMORY_SCOPE_AGENT);
            if (t == T_-1)
                *(float2*)&out[(size_t)TBH + (size_t)gb*H_ + n0 + ec0] = make_float2(y0, y1);
        }
        // prefetch next xw (latency hides under next step's h polling)
        if (t + 1 < T_)
            xwv = *(const float2*)&out[(size_t)((t+1)*B_ + row_g + er)*H_ + n0 + ec0];
        // no further barrier: partials are parity-double-buffered, and the t+2
        // same-parity overwrite is separated from this step's read by t+1's
        // __syncthreads (every thread passes it after its t-read).
    }
}

// ---- host --------------------------------------------------------------------
extern "C" void kernel_launch(void* const* d_in, const int* in_sizes, int n_in,
                              void* d_out, int out_size, void* d_ws, size_t ws_size,
                              hipStream_t stream) {
    const float* x    = (const float*)d_in[0];
    const float* h0   = (const float*)d_in[1];
    const float* Wx   = (const float*)d_in[2];
    const float* Wh   = (const float*)d_in[3];
    const float* bias = (const float*)d_in[4];
    float* out = (float*)d_out;

    const size_t nX = (size_t)T_ * B_ * IN_;            // 16,777,216
    const size_t nWx = (size_t)IN_ * H_;                // 524,288
    const size_t hbufB = (size_t)2 * HB * sizeof(u32);  // 512 KB tagged-f32 ping-pong
    const size_t FULL_NEED = 2*nX*2 + 2*nWx*2 + hbufB;  // ~66.5 MiB
    const size_t SAFE_NEED = hbufB;
    if (ws_size < SAFE_NEED) return;   // cannot run; fail loudly

    bool full = ws_size >= FULL_NEED;
    u16 *xhi = nullptr, *xlo = nullptr, *wthi = nullptr, *wtlo = nullptr;
    u32* hbuf;
    if (full) {
        xhi  = (u16*)d_ws;
        xlo  = xhi + nX;
        wthi = xlo + nX;
        wtlo = wthi + nWx;
        hbuf = (u32*)(wtlo + nWx);
    } else {
        hbuf = (u32*)d_ws;
    }

    // zero hbuf: tag 0 can never validate (tags are 64..127); poison 0xAA = tag 42 also safe
    hipMemsetAsync(hbuf, 0, hbufB, stream);
    k_h0<<<HB/256, 256, 0, stream>>>(h0, hbuf);
    if (full) {
        k_split4<<<2048, 256, 0, stream>>>((const float4*)x, xhi, xlo, (int)(nX/4));
        k_tsplit<<<(int)(nWx/256), 256, 0, stream>>>(Wx, wthi, wtlo, IN_, H_);
        k_gemm_xw<<<2048, 256, 0, stream>>>(xhi, xlo, wthi, wtlo, bias, out);
    } else {
        k_gemm_f32<<<dim3(16, 512), 256, 0, stream>>>(x, Wx, bias, out);
    }
    k_scan<<<128, 256, 0, stream>>>(Wh, out, hbuf);
}

// Round 6
// 3301.204 us; speedup vs baseline: 1.6560x; 1.0797x over previous
//
#include <hip/hip_runtime.h>
#include <hip/hip_bf16.h>

// RNN: outs[t] = h_t = tanh(x[t]@Wx + b + h_{t-1}@Wh), T=512,B=64,IN=512,H=1024
//  - split-bf16 (hi+lo) MFMA everywhere (no fp32 MFMA on CDNA4); 3-term product
//  - phase A: xw = x@Wx+b written directly into d_out (overwritten by h_t in place)
//  - scan: 128 persistent wgs = 4 batch-groups(16 rows) x 32 col-groups(32 cols),
//    Wh register-resident, self-validating tagged-f32 h (low 7 mantissa bits =
//    epoch tag 64|(t&63); the poll IS the data load).
//  - R1: coherent-h only (no fences): 15.5 -> 9.5 us/step.
//  - R2: lock-free flag barrier: REGRESSED -> cost is serialized coherence legs.
//  - R3: self-validating h: 9.5 -> 6.4 us/step.
//  - R4: XCD-local fast path: DEADLOCK (600s). Spin progress depended on
//    unverified same-XCD visibility of plain stores. Lesson: polled bytes must
//    travel through architecturally-coherent ops only. Reverted.
//  - R5: (a) producer h-stores become atomic-swap RMWs (execute AT the
//    coherence cache, line stays resident; no write-through-to-HBM leg);
//    (b) chunk-granular poll revalidation (wave-uniform 16-bit pending mask,
//    one chunk = one producer stripe) cuts retry fetch + tag-check VALU;
//    (c) u64 tag checks (half the ALU ops).

#define T_ 512
#define B_ 64
#define IN_ 512
#define H_ 1024
constexpr int TBH = T_ * B_ * H_;   // 33,554,432
constexpr int HB  = B_ * H_;        // 65,536

typedef unsigned short u16;
typedef unsigned int u32;
typedef unsigned long long u64;
typedef __attribute__((ext_vector_type(8))) short short8;   // 8 x bf16 (4 VGPRs)
typedef __attribute__((ext_vector_type(4))) float f32x4;

__device__ __forceinline__ void splitbf(float x, u16& hi, u16& lo) {
    unsigned u = __float_as_uint(x);
    hi = (u16)(u >> 16);                       // truncated bf16 hi
    float r = x - __uint_as_float(u & 0xffff0000u);
    lo = (u16)(__float_as_uint(r) >> 16);      // bf16 of residual; total rel err ~2^-16
}

// ---- prep kernels ------------------------------------------------------------
__global__ void k_split4(const float4* __restrict__ in, u16* __restrict__ hi,
                         u16* __restrict__ lo, int n4) {
    int i = blockIdx.x * blockDim.x + threadIdx.x;
    int stride = gridDim.x * blockDim.x;
    for (; i < n4; i += stride) {
        float4 v = in[i];
        u16 h0,h1,h2,h3,l0,l1,l2,l3;
        splitbf(v.x,h0,l0); splitbf(v.y,h1,l1); splitbf(v.z,h2,l2); splitbf(v.w,h3,l3);
        uint2 hv, lv;
        hv.x = (unsigned)h0 | ((unsigned)h1 << 16);
        hv.y = (unsigned)h2 | ((unsigned)h3 << 16);
        lv.x = (unsigned)l0 | ((unsigned)l1 << 16);
        lv.y = (unsigned)l2 | ((unsigned)l3 << 16);
        *(uint2*)&hi[4*i] = hv;
        *(uint2*)&lo[4*i] = lv;
    }
}

// src [K][N] fp32 -> dst [N][K] bf16 hi/lo (transposed for B-fragment reads)
__global__ void k_tsplit(const float* __restrict__ src, u16* __restrict__ hi,
                         u16* __restrict__ lo, int K, int N) {
    int id = blockIdx.x * 256 + threadIdx.x;
    if (id >= K * N) return;
    int k = id / N, n = id % N;
    u16 h, l; splitbf(src[id], h, l);
    hi[n*K + k] = h; lo[n*K + k] = l;
}

// h0 fp32 -> tagged-f32 into hbuf parity-1 (read at t=0, expects tag 127)
__global__ void k_h0(const float* __restrict__ h0, u32* __restrict__ hbuf) {
    int id = blockIdx.x * 256 + threadIdx.x;
    if (id >= HB) return;
    u32 u = __float_as_uint(h0[id]);
    hbuf[HB + id] = (u & 0xFFFFFF80u) | 127u;   // tag(t=-1) = 64|63 = 127
}

// ---- phase A: xw = x@Wx + b, split-bf16 MFMA, 128x128 tile, frags from global -
__launch_bounds__(256, 2)
__global__ void k_gemm_xw(const u16* __restrict__ xhi, const u16* __restrict__ xlo,
                          const u16* __restrict__ wthi, const u16* __restrict__ wtlo,
                          const float* __restrict__ bias, float* __restrict__ out) {
    int bid = blockIdx.x;
    int mi = bid >> 3, ni = bid & 7;
    int m0 = mi * 128, n0 = ni * 128;
    int wave = threadIdx.x >> 6, lane = threadIdx.x & 63;
    int wr = wave >> 1, wc = wave & 1;
    int lrow = lane & 15, lk8 = (lane >> 4) * 8;
    const int rowb = m0 + wr*64 + lrow;   // A row for this lane
    const int colb = n0 + wc*64 + lrow;   // B col for this lane
    f32x4 acc[4][4] = {};
    for (int kt = 0; kt < 16; ++kt) {
        int kb = kt*32 + lk8;
        short8 ah[4], al[4], bh[4], bl[4];
#pragma unroll
        for (int mt = 0; mt < 4; ++mt) {
            ah[mt] = *(const short8*)&xhi[(size_t)(rowb + mt*16)*IN_ + kb];
            al[mt] = *(const short8*)&xlo[(size_t)(rowb + mt*16)*IN_ + kb];
        }
#pragma unroll
        for (int nt = 0; nt < 4; ++nt) {
            bh[nt] = *(const short8*)&wthi[(size_t)(colb + nt*16)*IN_ + kb];
            bl[nt] = *(const short8*)&wtlo[(size_t)(colb + nt*16)*IN_ + kb];
        }
#pragma unroll
        for (int mt = 0; mt < 4; ++mt)
#pragma unroll
            for (int nt = 0; nt < 4; ++nt) {
                acc[mt][nt] = __builtin_amdgcn_mfma_f32_16x16x32_bf16(ah[mt], bh[nt], acc[mt][nt], 0,0,0);
                acc[mt][nt] = __builtin_amdgcn_mfma_f32_16x16x32_bf16(ah[mt], bl[nt], acc[mt][nt], 0,0,0);
                acc[mt][nt] = __builtin_amdgcn_mfma_f32_16x16x32_bf16(al[mt], bh[nt], acc[mt][nt], 0,0,0);
            }
    }
    // epilogue: D layout col=lane&15, row=4*(lane>>4)+reg
    int orow0 = m0 + wr*64 + 4*(lane >> 4);
#pragma unroll
    for (int nt = 0; nt < 4; ++nt) {
        int col = n0 + wc*64 + nt*16 + (lane & 15);
        float bv = bias[col];
#pragma unroll
        for (int mt = 0; mt < 4; ++mt)
#pragma unroll
            for (int r = 0; r < 4; ++r)
                out[(size_t)(orow0 + mt*16 + r)*H_ + col] = acc[mt][nt][r] + bv;
    }
}

// ---- phase A fallback (fp32 vector) if ws too small for split buffers --------
__global__ void k_gemm_f32(const float* __restrict__ A, const float* __restrict__ Bw,
                           const float* __restrict__ bias, float* __restrict__ out) {
    __shared__ float As[32][65];  // [k][m]
    __shared__ float Bs[32][65];  // [k][n]
    int n0 = blockIdx.x * 64, m0 = blockIdx.y * 64;
    int tid = threadIdx.x;
    int tr = tid >> 4, tc = tid & 15;
    float acc[4][4] = {};
    for (int kc = 0; kc < IN_; kc += 32) {
#pragma unroll
        for (int it = 0; it < 8; ++it) {
            int id = tid + 256*it;
            int k = id & 31, m = id >> 5;
            As[k][m] = A[(size_t)(m0 + m)*IN_ + kc + k];
        }
#pragma unroll
        for (int it = 0; it < 8; ++it) {
            int id = tid + 256*it;
            int n = id & 63, kk = id >> 6;
            Bs[kk][n] = Bw[(size_t)(kc + kk)*H_ + n0 + n];
        }
        __syncthreads();
#pragma unroll
        for (int kk = 0; kk < 32; ++kk) {
            float a[4], b[4];
#pragma unroll
            for (int i = 0; i < 4; ++i) a[i] = As[kk][tr*4+i];
#pragma unroll
            for (int j = 0; j < 4; ++j) b[j] = Bs[kk][tc*4+j];
#pragma unroll
            for (int i = 0; i < 4; ++i)
#pragma unroll
                for (int j = 0; j < 4; ++j) acc[i][j] += a[i]*b[j];
        }
        __syncthreads();
    }
#pragma unroll
    for (int i = 0; i < 4; ++i)
#pragma unroll
        for (int j = 0; j < 4; ++j)
            out[(size_t)(m0 + tr*4 + i)*H_ + n0 + tc*4 + j] = acc[i][j] + bias[n0 + tc*4 + j];
}

// ---- scan: persistent, Wh register-resident, self-validating h exchange ------
__launch_bounds__(256, 1)
__global__ void k_scan(const float* __restrict__ wh,   // [H][H] fp32 (k-major)
                       float* __restrict__ out,        // [T][B][H] xw in / h out, + h_last tail
                       u32* __restrict__ hbuf) {       // [2 parity][B][H] tagged f32
    int bid = blockIdx.x;
    int g = bid >> 5, cg = bid & 31;
    int n0 = cg * 32;
    int row_g = g * 16;
    int wave = threadIdx.x >> 6, lane = threadIdx.x & 63;
    int lrow = lane & 15, lk8 = (lane >> 4) * 8;
    __shared__ float partial[2 * 4 * 16 * 33];   // [parity][wave][row][col(+pad)]

    // Load Wh fragments ONCE: this wave covers k in [wave*256, wave*256+256)
    short8 bh[2][8], bl[2][8];
#pragma unroll
    for (int nt = 0; nt < 2; ++nt) {
        int col = n0 + nt*16 + lrow;
#pragma unroll
        for (int kt = 0; kt < 8; ++kt) {
            int kbase = wave*256 + kt*32 + lk8;
            short8 h8, l8;
#pragma unroll
            for (int j = 0; j < 8; ++j) {
                u16 hh, ll; splitbf(wh[(size_t)(kbase + j)*H_ + col], hh, ll);
                h8[j] = (short)hh; l8[j] = (short)ll;
            }
            bh[nt][kt] = h8; bl[nt][kt] = l8;
        }
    }

    // epilogue indexing: row er, col-pair ec0
    const int er = threadIdx.x >> 4;         // 0..15
    const int ec0 = (threadIdx.x & 15) * 2;  // 0,2,..,30

    // prefetch xw for t=0
    float2 xwv = *(const float2*)&out[(size_t)(0*B_ + row_g + er)*H_ + n0 + ec0];

    for (int t = 0; t < T_; ++t) {
        const u32* hprev = hbuf + (size_t)((t+1)&1)*HB;   // h_{t-1} tagged
        u32* hnew = hbuf + (size_t)(t&1)*HB;              // h_t tagged
        const u32 want = 64u | (u32)((t - 1) & 63);
        const u64 want64 = ((u64)want << 32) | (u64)want;
        const int par = t & 1;

        // ---- self-validating retry-load, chunk-granular revalidation ----
        // chunk c (0..15) = u64s {2c, 2c+1} = words [4c..4c+4); one producer stripe
        u64 raw[32];
        const u64* base = (const u64*)&hprev[(size_t)(row_g + lrow)*H_ + wave*256 + lk8];
        u32 pend = 0xFFFFu;                  // wave-uniform pending-chunk mask
        for (;;) {
#pragma unroll
            for (int c = 0; c < 16; ++c) {
                if (pend & (1u << c)) {
                    const u64* p = base + (c >> 1) * 16 + (c & 1) * 2;
                    raw[2*c]   = __hip_atomic_load(p,   __ATOMIC_RELAXED, __HIP_MEMORY_SCOPE_AGENT);
                    raw[2*c+1] = __hip_atomic_load(p+1, __ATOMIC_RELAXED, __HIP_MEMORY_SCOPE_AGENT);
                }
            }
            u32 np = 0;
#pragma unroll
            for (int c = 0; c < 16; ++c) {
                if (pend & (1u << c)) {
                    u64 bad = ((raw[2*c] ^ want64) | (raw[2*c+1] ^ want64))
                              & 0x0000007F0000007FULL;
                    if (__any(bad != 0)) np |= 1u << c;
                }
            }
            pend = np;
            if (pend == 0) break;
            __builtin_amdgcn_s_sleep(1);
        }

        // ---- convert tagged f32 -> bf16 hi/lo fragments ----
        // word j of kt lives in raw[kt*4 + (j>>1)], half (j&1)
        short8 ah[8], al[8];
#pragma unroll
        for (int kt = 0; kt < 8; ++kt) {
#pragma unroll
            for (int j = 0; j < 8; ++j) {
                u32 bits = (j & 1) ? (u32)(raw[kt*4 + (j>>1)] >> 32)
                                   : (u32)(raw[kt*4 + (j>>1)]);
                ah[kt][j] = (short)(bits >> 16);
                float r = __uint_as_float(bits & 0xFFFFFF80u)
                        - __uint_as_float(bits & 0xFFFF0000u);
                al[kt][j] = (short)(__float_as_uint(r) >> 16);
            }
        }

        // ---- MFMA (parity-split chains) ----
        f32x4 acc[2][2] = {};
#pragma unroll
        for (int kt = 0; kt < 8; ++kt) {
            int p = kt & 1;
#pragma unroll
            for (int nt = 0; nt < 2; ++nt) {
                acc[nt][p] = __builtin_amdgcn_mfma_f32_16x16x32_bf16(ah[kt], bh[nt][kt], acc[nt][p], 0,0,0);
                acc[nt][p] = __builtin_amdgcn_mfma_f32_16x16x32_bf16(ah[kt], bl[nt][kt], acc[nt][p], 0,0,0);
                acc[nt][p] = __builtin_amdgcn_mfma_f32_16x16x32_bf16(al[kt], bh[nt][kt], acc[nt][p], 0,0,0);
            }
        }
        // K-partials to LDS (parity double-buffer): row=4*(lane>>4)+r, col=nt*16+lrow
        {
            int r0 = 4 * (lane >> 4);
#pragma unroll
            for (int nt = 0; nt < 2; ++nt) {
                int c = nt*16 + lrow;
#pragma unroll
                for (int r = 0; r < 4; ++r)
                    partial[((par*4 + wave)*16 + r0 + r)*33 + c] = acc[nt][0][r] + acc[nt][1][r];
            }
        }
        __syncthreads();
        // ---- reduce + tanh + stores ----
        {
            float s0 = xwv.x, s1 = xwv.y;
#pragma unroll
            for (int w = 0; w < 4; ++w) {
                s0 += partial[((par*4 + w)*16 + er)*33 + ec0];
                s1 += partial[((par*4 + w)*16 + er)*33 + ec0 + 1];
            }
            float y0 = tanhf(s0), y1 = tanhf(s1);
            int gb = row_g + er;
            *(float2*)&out[(size_t)(t*B_ + gb)*H_ + n0 + ec0] = make_float2(y0, y1);
            const u32 tagt = 64u | (u32)(t & 63);
            u32 b0 = (__float_as_uint(y0) & 0xFFFFFF80u) | tagt;
            u32 b1 = (__float_as_uint(y1) & 0xFFFFFF80u) | tagt;
            // atomic-swap RMW: executes AT the coherence cache; line stays
            // resident there (no write-through-to-HBM leg). Result unused.
            (void)__hip_atomic_exchange((u64*)&hnew[(size_t)gb*H_ + n0 + ec0],
                                        ((u64)b1 << 32) | (u64)b0,
                                        __ATOMIC_RELAXED, __HIP_MEMORY_SCOPE_AGENT);
            if (t == T_-1)
                *(float2*)&out[(size_t)TBH + (size_t)gb*H_ + n0 + ec0] = make_float2(y0, y1);
        }
        // prefetch next xw (latency hides under next step's h polling)
        if (t + 1 < T_)
            xwv = *(const float2*)&out[(size_t)((t+1)*B_ + row_g + er)*H_ + n0 + ec0];
        // parity-double-buffered partials: t+2's same-parity overwrite is
        // separated from t's read by t+1's __syncthreads.
    }
}

// ---- host --------------------------------------------------------------------
extern "C" void kernel_launch(void* const* d_in, const int* in_sizes, int n_in,
                              void* d_out, int out_size, void* d_ws, size_t ws_size,
                              hipStream_t stream) {
    const float* x    = (const float*)d_in[0];
    const float* h0   = (const float*)d_in[1];
    const float* Wx   = (const float*)d_in[2];
    const float* Wh   = (const float*)d_in[3];
    const float* bias = (const float*)d_in[4];
    float* out = (float*)d_out;

    const size_t nX = (size_t)T_ * B_ * IN_;            // 16,777,216
    const size_t nWx = (size_t)IN_ * H_;                // 524,288
    const size_t hbufB = (size_t)2 * HB * sizeof(u32);  // 512 KB tagged-f32 ping-pong
    const size_t FULL_NEED = 2*nX*2 + 2*nWx*2 + hbufB;  // ~66.5 MiB
    const size_t SAFE_NEED = hbufB;
    if (ws_size < SAFE_NEED) return;   // cannot run; fail loudly

    bool full = ws_size >= FULL_NEED;
    u16 *xhi = nullptr, *xlo = nullptr, *wthi = nullptr, *wtlo = nullptr;
    u32* hbuf;
    if (full) {
        xhi  = (u16*)d_ws;
        xlo  = xhi + nX;
        wthi = xlo + nX;
        wtlo = wthi + nWx;
        hbuf = (u32*)(wtlo + nWx);
    } else {
        hbuf = (u32*)d_ws;
    }

    // zero hbuf: tag 0 can never validate (tags are 64..127); poison 0xAA = tag 42 safe
    hipMemsetAsync(hbuf, 0, hbufB, stream);
    k_h0<<<HB/256, 256, 0, stream>>>(h0, hbuf);
    if (full) {
        k_split4<<<2048, 256, 0, stream>>>((const float4*)x, xhi, xlo, (int)(nX/4));
        k_tsplit<<<(int)(nWx/256), 256, 0, stream>>>(Wx, wthi, wtlo, IN_, H_);
        k_gemm_xw<<<2048, 256, 0, stream>>>(xhi, xlo, wthi, wtlo, bias, out);
    } else {
        k_gemm_f32<<<dim3(16, 512), 256, 0, stream>>>(x, Wx, bias, out);
    }
    k_scan<<<128, 256, 0, stream>>>(Wh, out, hbuf);
}

// Round 7
// 2589.571 us; speedup vs baseline: 2.1111x; 1.2748x over previous
//
#include <hip/hip_runtime.h>
#include <hip/hip_bf16.h>

// RNN: outs[t] = h_t = tanh(x[t]@Wx + b + h_{t-1}@Wh), T=512,B=64,IN=512,H=1024
//  - split-bf16 (hi+lo) MFMA everywhere (no fp32 MFMA on CDNA4); 3-term product
//  - phase A: xw = x@Wx+b written directly into d_out (overwritten by h_t in place)
//  - scan: 128 persistent wgs = 4 batch-groups(16 rows) x 32 col-groups(32 cols),
//    Wh register-resident, self-validating tagged-f32 h (low 7 mantissa bits =
//    epoch tag 64|(t&63); the poll IS the data load).
//  - R1: coherent-h only: 15.5 -> 9.5 us/step.  R2: flag barrier: REGRESSED.
//  - R3: self-validating h: 9.5 -> 6.4.  R4: XCD-local fast path: DEADLOCK.
//  - R5: swap-RMW stores + chunk retries: 6.4 -> 5.9. FETCH unchanged -> the
//    limiter is IC REQUEST CONGESTION: agent loads bypass L1/L2 (no line reuse),
//    and the [row][K] layout scatters each poll sweep into ~512 requests/wave.
//  - R6: group-packed col-major h layout [g][par][1024 k][16 r]: poll loads are
//    per-instr CONTIGUOUS (4 lines/instr, 128 req/wave/sweep, 4x fewer);
//    validated slice is lane-transposed vs MFMA fragments -> LDS bounce
//    (write [r][1030] 2-way-free, read 8-f32 runs ~4-way). Producer h-stores
//    remapped to contiguous u64 swaps (4 req/wave).

#define T_ 512
#define B_ 64
#define IN_ 512
#define H_ 1024
constexpr int TBH = T_ * B_ * H_;   // 33,554,432
constexpr int HB  = B_ * H_;        // 65,536
constexpr int GP  = 1024 * 16;      // u32s per (group,parity) packed slice

typedef unsigned short u16;
typedef unsigned int u32;
typedef unsigned long long u64;
typedef __attribute__((ext_vector_type(8))) short short8;   // 8 x bf16 (4 VGPRs)
typedef __attribute__((ext_vector_type(4))) float f32x4;

__device__ __forceinline__ void splitbf(float x, u16& hi, u16& lo) {
    unsigned u = __float_as_uint(x);
    hi = (u16)(u >> 16);                       // truncated bf16 hi
    float r = x - __uint_as_float(u & 0xffff0000u);
    lo = (u16)(__float_as_uint(r) >> 16);      // bf16 of residual; total rel err ~2^-16
}

// ---- prep kernels ------------------------------------------------------------
__global__ void k_split4(const float4* __restrict__ in, u16* __restrict__ hi,
                         u16* __restrict__ lo, int n4) {
    int i = blockIdx.x * blockDim.x + threadIdx.x;
    int stride = gridDim.x * blockDim.x;
    for (; i < n4; i += stride) {
        float4 v = in[i];
        u16 h0,h1,h2,h3,l0,l1,l2,l3;
        splitbf(v.x,h0,l0); splitbf(v.y,h1,l1); splitbf(v.z,h2,l2); splitbf(v.w,h3,l3);
        uint2 hv, lv;
        hv.x = (unsigned)h0 | ((unsigned)h1 << 16);
        hv.y = (unsigned)h2 | ((unsigned)h3 << 16);
        lv.x = (unsigned)l0 | ((unsigned)l1 << 16);
        lv.y = (unsigned)l2 | ((unsigned)l3 << 16);
        *(uint2*)&hi[4*i] = hv;
        *(uint2*)&lo[4*i] = lv;
    }
}

// src [K][N] fp32 -> dst [N][K] bf16 hi/lo (transposed for B-fragment reads)
__global__ void k_tsplit(const float* __restrict__ src, u16* __restrict__ hi,
                         u16* __restrict__ lo, int K, int N) {
    int id = blockIdx.x * 256 + threadIdx.x;
    if (id >= K * N) return;
    int k = id / N, n = id % N;
    u16 h, l; splitbf(src[id], h, l);
    hi[n*K + k] = h; lo[n*K + k] = l;
}

// h0 fp32 [B][H] -> packed tagged-f32 parity-1 (read at t=0, expects tag 127)
__global__ void k_h0(const float* __restrict__ h0, u32* __restrict__ hbufP) {
    int id = blockIdx.x * 256 + threadIdx.x;
    if (id >= HB) return;
    int b = id >> 10, k = id & 1023;
    u32 u = __float_as_uint(h0[id]);
    hbufP[(size_t)((b>>4)*2 + 1)*GP + k*16 + (b & 15)] = (u & 0xFFFFFF80u) | 127u;
}

// ---- phase A: xw = x@Wx + b, split-bf16 MFMA, 128x128 tile, frags from global -
__launch_bounds__(256, 2)
__global__ void k_gemm_xw(const u16* __restrict__ xhi, const u16* __restrict__ xlo,
                          const u16* __restrict__ wthi, const u16* __restrict__ wtlo,
                          const float* __restrict__ bias, float* __restrict__ out) {
    int bid = blockIdx.x;
    int mi = bid >> 3, ni = bid & 7;
    int m0 = mi * 128, n0 = ni * 128;
    int wave = threadIdx.x >> 6, lane = threadIdx.x & 63;
    int wr = wave >> 1, wc = wave & 1;
    int lrow = lane & 15, lk8 = (lane >> 4) * 8;
    const int rowb = m0 + wr*64 + lrow;   // A row for this lane
    const int colb = n0 + wc*64 + lrow;   // B col for this lane
    f32x4 acc[4][4] = {};
    for (int kt = 0; kt < 16; ++kt) {
        int kb = kt*32 + lk8;
        short8 ah[4], al[4], bh[4], bl[4];
#pragma unroll
        for (int mt = 0; mt < 4; ++mt) {
            ah[mt] = *(const short8*)&xhi[(size_t)(rowb + mt*16)*IN_ + kb];
            al[mt] = *(const short8*)&xlo[(size_t)(rowb + mt*16)*IN_ + kb];
        }
#pragma unroll
        for (int nt = 0; nt < 4; ++nt) {
            bh[nt] = *(const short8*)&wthi[(size_t)(colb + nt*16)*IN_ + kb];
            bl[nt] = *(const short8*)&wtlo[(size_t)(colb + nt*16)*IN_ + kb];
        }
#pragma unroll
        for (int mt = 0; mt < 4; ++mt)
#pragma unroll
            for (int nt = 0; nt < 4; ++nt) {
                acc[mt][nt] = __builtin_amdgcn_mfma_f32_16x16x32_bf16(ah[mt], bh[nt], acc[mt][nt], 0,0,0);
                acc[mt][nt] = __builtin_amdgcn_mfma_f32_16x16x32_bf16(ah[mt], bl[nt], acc[mt][nt], 0,0,0);
                acc[mt][nt] = __builtin_amdgcn_mfma_f32_16x16x32_bf16(al[mt], bh[nt], acc[mt][nt], 0,0,0);
            }
    }
    // epilogue: D layout col=lane&15, row=4*(lane>>4)+reg
    int orow0 = m0 + wr*64 + 4*(lane >> 4);
#pragma unroll
    for (int nt = 0; nt < 4; ++nt) {
        int col = n0 + wc*64 + nt*16 + (lane & 15);
        float bv = bias[col];
#pragma unroll
        for (int mt = 0; mt < 4; ++mt)
#pragma unroll
            for (int r = 0; r < 4; ++r)
                out[(size_t)(orow0 + mt*16 + r)*H_ + col] = acc[mt][nt][r] + bv;
    }
}

// ---- phase A fallback (fp32 vector) if ws too small for split buffers --------
__global__ void k_gemm_f32(const float* __restrict__ A, const float* __restrict__ Bw,
                           const float* __restrict__ bias, float* __restrict__ out) {
    __shared__ float As[32][65];  // [k][m]
    __shared__ float Bs[32][65];  // [k][n]
    int n0 = blockIdx.x * 64, m0 = blockIdx.y * 64;
    int tid = threadIdx.x;
    int tr = tid >> 4, tc = tid & 15;
    float acc[4][4] = {};
    for (int kc = 0; kc < IN_; kc += 32) {
#pragma unroll
        for (int it = 0; it < 8; ++it) {
            int id = tid + 256*it;
            int k = id & 31, m = id >> 5;
            As[k][m] = A[(size_t)(m0 + m)*IN_ + kc + k];
        }
#pragma unroll
        for (int it = 0; it < 8; ++it) {
            int id = tid + 256*it;
            int n = id & 63, kk = id >> 6;
            Bs[kk][n] = Bw[(size_t)(kc + kk)*H_ + n0 + n];
        }
        __syncthreads();
#pragma unroll
        for (int kk = 0; kk < 32; ++kk) {
            float a[4], b[4];
#pragma unroll
            for (int i = 0; i < 4; ++i) a[i] = As[kk][tr*4+i];
#pragma unroll
            for (int j = 0; j < 4; ++j) b[j] = Bs[kk][tc*4+j];
#pragma unroll
            for (int i = 0; i < 4; ++i)
#pragma unroll
                for (int j = 0; j < 4; ++j) acc[i][j] += a[i]*b[j];
        }
        __syncthreads();
    }
#pragma unroll
    for (int i = 0; i < 4; ++i)
#pragma unroll
        for (int j = 0; j < 4; ++j)
            out[(size_t)(m0 + tr*4 + i)*H_ + n0 + tc*4 + j] = acc[i][j] + bias[n0 + tc*4 + j];
}

// ---- scan: persistent, Wh register-resident, packed self-validating exchange -
__launch_bounds__(256, 1)
__global__ void k_scan(const float* __restrict__ wh,   // [H][H] fp32 (k-major)
                       float* __restrict__ out,        // [T][B][H] xw in / h out, + h_last tail
                       u32* __restrict__ hbufP) {      // [4 g][2 par][1024 k][16 r] tagged f32
    int bid = blockIdx.x;
    int g = bid >> 5, cg = bid & 31;
    int n0 = cg * 32;
    int row_g = g * 16;
    int wave = threadIdx.x >> 6, lane = threadIdx.x & 63;
    int lrow = lane & 15, lk8 = (lane >> 4) * 8;
    __shared__ float partial[2 * 4 * 16 * 33];   // [parity][wave][row][col(+pad)]
    __shared__ float hx[16 * 1030];              // [row][k] bounce, stride 1030

    // Load Wh fragments ONCE: this wave covers k in [wave*256, wave*256+256)
    short8 bh[2][8], bl[2][8];
#pragma unroll
    for (int nt = 0; nt < 2; ++nt) {
        int col = n0 + nt*16 + lrow;
#pragma unroll
        for (int kt = 0; kt < 8; ++kt) {
            int kbase = wave*256 + kt*32 + lk8;
            short8 h8, l8;
#pragma unroll
            for (int j = 0; j < 8; ++j) {
                u16 hh, ll; splitbf(wh[(size_t)(kbase + j)*H_ + col], hh, ll);
                h8[j] = (short)hh; l8[j] = (short)ll;
            }
            bh[nt][kt] = h8; bl[nt][kt] = l8;
        }
    }

    // epilogue mapping: thread = (col ec, row-pair er0)
    const int ec  = threadIdx.x >> 3;        // 0..31 wg-local col
    const int er0 = (threadIdx.x & 7) * 2;   // 0,2,..,14 group-local row

    // prefetch xw for t=0 (rows er0, er0+1 of col n0+ec)
    float xw0 = out[(size_t)(row_g + er0    )*H_ + n0 + ec];
    float xw1 = out[(size_t)(row_g + er0 + 1)*H_ + n0 + ec];

    for (int t = 0; t < T_; ++t) {
        const u32 want = 64u | (u32)((t - 1) & 63);
        const u64 want64 = ((u64)want << 32) | (u64)want;
        const int par = t & 1;

        // ---- self-validating poll of this wave's CONTIGUOUS 16KB slice ----
        // slice = cols [wave*256, +256) x 16 rows, packed [k][r16].
        // instr i: lanes load u64 #(i*64+lane) -> 512B contiguous = 4 lines.
        u64 raw[32];
        const u64* sb = (const u64*)(hbufP + (size_t)(g*2 + ((t+1)&1))*GP) + wave*2048;
        u32 pend = 0xFFFFFFFFu;
        for (;;) {
#pragma unroll
            for (int i = 0; i < 32; ++i)
                if (pend & (1u << i))
                    raw[i] = __hip_atomic_load(sb + i*64 + lane, __ATOMIC_RELAXED,
                                               __HIP_MEMORY_SCOPE_AGENT);
            u32 np = 0;
#pragma unroll
            for (int i = 0; i < 32; ++i)
                if (pend & (1u << i)) {
                    u64 bad = (raw[i] ^ want64) & 0x0000007F0000007FULL;
                    if (__any(bad != 0)) np |= 1u << i;
                }
            pend = np;
            if (pend == 0) break;
            __builtin_amdgcn_s_sleep(1);
        }

        // ---- bounce to LDS [row][k] (lane-transpose). u64 #i = col
        // wave*256 + i*8 + (lane>>3), rows 2*(lane&7), +1.
        {
            int colb = wave*256 + (lane >> 3);
            int r = 2 * (lane & 7);
#pragma unroll
            for (int i = 0; i < 32; ++i) {
                int col = colb + i*8;
                hx[r*1030 + col]       = __uint_as_float((u32)raw[i]);
                hx[(r+1)*1030 + col]   = __uint_as_float((u32)(raw[i] >> 32));
            }
        }
        asm volatile("s_waitcnt lgkmcnt(0)" ::: "memory");
        __builtin_amdgcn_sched_barrier(0);   // keep fragment reads below the wait

        // ---- fragments from LDS + convert + MFMA (parity-split chains) ----
        f32x4 acc[2][2] = {};
#pragma unroll
        for (int kt = 0; kt < 8; ++kt) {
            int p = kt & 1;
            short8 ah, al;
            int cb = lrow*1030 + wave*256 + kt*32 + lk8;
#pragma unroll
            for (int j = 0; j < 8; ++j) {
                u32 bits = __float_as_uint(hx[cb + j]);
                ah[j] = (short)(bits >> 16);
                float r = __uint_as_float(bits & 0xFFFFFF80u)
                        - __uint_as_float(bits & 0xFFFF0000u);
                al[j] = (short)(__float_as_uint(r) >> 16);
            }
#pragma unroll
            for (int nt = 0; nt < 2; ++nt) {
                acc[nt][p] = __builtin_amdgcn_mfma_f32_16x16x32_bf16(ah, bh[nt][kt], acc[nt][p], 0,0,0);
                acc[nt][p] = __builtin_amdgcn_mfma_f32_16x16x32_bf16(ah, bl[nt][kt], acc[nt][p], 0,0,0);
                acc[nt][p] = __builtin_amdgcn_mfma_f32_16x16x32_bf16(al, bh[nt][kt], acc[nt][p], 0,0,0);
            }
        }
        // K-partials to LDS (parity dbuf): row=4*(lane>>4)+r, col=nt*16+lrow
        {
            int r0 = 4 * (lane >> 4);
#pragma unroll
            for (int nt = 0; nt < 2; ++nt) {
                int c = nt*16 + lrow;
#pragma unroll
                for (int r = 0; r < 4; ++r)
                    partial[((par*4 + wave)*16 + r0 + r)*33 + c] = acc[nt][0][r] + acc[nt][1][r];
            }
        }
        __syncthreads();
        // ---- reduce + tanh + stores (thread = (ec, er0/er0+1)) ----
        {
            float s0 = xw0, s1 = xw1;
#pragma unroll
            for (int w = 0; w < 4; ++w) {
                s0 += partial[((par*4 + w)*16 + er0    )*33 + ec];
                s1 += partial[((par*4 + w)*16 + er0 + 1)*33 + ec];
            }
            float y0 = tanhf(s0), y1 = tanhf(s1);
            int gb0 = row_g + er0;
            out[(size_t)(t*B_ + gb0    )*H_ + n0 + ec] = y0;
            out[(size_t)(t*B_ + gb0 + 1)*H_ + n0 + ec] = y1;
            const u32 tagt = 64u | (u32)(t & 63);
            u32 b0 = (__float_as_uint(y0) & 0xFFFFFF80u) | tagt;
            u32 b1 = (__float_as_uint(y1) & 0xFFFFFF80u) | tagt;
            // packed store: [col n0+ec][rows er0,er0+1] -> one contiguous u64 swap.
            u32* hnb = hbufP + (size_t)(g*2 + par)*GP + (n0 + ec)*16 + er0;
            (void)__hip_atomic_exchange((u64*)hnb, ((u64)b1 << 32) | (u64)b0,
                                        __ATOMIC_RELAXED, __HIP_MEMORY_SCOPE_AGENT);
            if (t == T_-1) {
                out[(size_t)TBH + (size_t)gb0*H_ + n0 + ec] = y0;
                out[(size_t)TBH + (size_t)(gb0+1)*H_ + n0 + ec] = y1;
            }
        }
        // prefetch next xw (latency hides under next step's h polling)
        if (t + 1 < T_) {
            xw0 = out[(size_t)((t+1)*B_ + row_g + er0    )*H_ + n0 + ec];
            xw1 = out[(size_t)((t+1)*B_ + row_g + er0 + 1)*H_ + n0 + ec];
        }
        // parity-double-buffered partials: t+2's same-parity overwrite is
        // separated from t's read by t+1's __syncthreads.
    }
}

// ---- host --------------------------------------------------------------------
extern "C" void kernel_launch(void* const* d_in, const int* in_sizes, int n_in,
                              void* d_out, int out_size, void* d_ws, size_t ws_size,
                              hipStream_t stream) {
    const float* x    = (const float*)d_in[0];
    const float* h0   = (const float*)d_in[1];
    const float* Wx   = (const float*)d_in[2];
    const float* Wh   = (const float*)d_in[3];
    const float* bias = (const float*)d_in[4];
    float* out = (float*)d_out;

    const size_t nX = (size_t)T_ * B_ * IN_;            // 16,777,216
    const size_t nWx = (size_t)IN_ * H_;                // 524,288
    const size_t hbufB = (size_t)8 * GP * sizeof(u32);  // 512 KB packed ping-pong
    const size_t FULL_NEED = 2*nX*2 + 2*nWx*2 + hbufB;  // ~66.5 MiB
    const size_t SAFE_NEED = hbufB;
    if (ws_size < SAFE_NEED) return;   // cannot run; fail loudly

    bool full = ws_size >= FULL_NEED;
    u16 *xhi = nullptr, *xlo = nullptr, *wthi = nullptr, *wtlo = nullptr;
    u32* hbufP;
    if (full) {
        xhi  = (u16*)d_ws;
        xlo  = xhi + nX;
        wthi = xlo + nX;
        wtlo = wthi + nWx;
        hbufP = (u32*)(wtlo + nWx);
    } else {
        hbufP = (u32*)d_ws;
    }

    // zero hbufP: tag 0 can never validate (tags are 64..127); poison 0xAA = tag 42 safe
    hipMemsetAsync(hbufP, 0, hbufB, stream);
    k_h0<<<HB/256, 256, 0, stream>>>(h0, hbufP);
    if (full) {
        k_split4<<<2048, 256, 0, stream>>>((const float4*)x, xhi, xlo, (int)(nX/4));
        k_tsplit<<<(int)(nWx/256), 256, 0, stream>>>(Wx, wthi, wtlo, IN_, H_);
        k_gemm_xw<<<2048, 256, 0, stream>>>(xhi, xlo, wthi, wtlo, bias, out);
    } else {
        k_gemm_f32<<<dim3(16, 512), 256, 0, stream>>>(x, Wx, bias, out);
    }
    k_scan<<<128, 256, 0, stream>>>(Wh, out, hbufP);
}